// Round 6
// baseline (423.614 us; speedup 1.0000x reference)
//
#include <hip/hip_runtime.h>
#include <hip/hip_bf16.h>
#include <math.h>

#define TPB 256

typedef __attribute__((ext_vector_type(8))) short bfrag8;
typedef __attribute__((ext_vector_type(4))) float f32x4;

static __device__ __forceinline__ float bf2f(unsigned int u) {
  union { unsigned int i; float f; } c; c.i = u << 16; return c.f;
}
static __device__ __forceinline__ unsigned short f2bf(float f) {
  union { float f; unsigned int i; } c; c.f = f;
  unsigned int lsb = (c.i >> 16) & 1u;
  return (unsigned short)((c.i + 0x7fffu + lsb) >> 16);
}

// DPP row-rotate ring reduction within each 16-lane row.
#define DPP_ROR(v, C) __int_as_float(__builtin_amdgcn_update_dpp( \
    __float_as_int(v), __float_as_int(v), (C), 0xf, 0xf, false))
static __device__ __forceinline__ float red16(float p) {
  p += DPP_ROR(p, 0x121);  // row_ror:1
  p += DPP_ROR(p, 0x122);  // row_ror:2
  p += DPP_ROR(p, 0x124);  // row_ror:4
  p += DPP_ROR(p, 0x128);  // row_ror:8
  return p;
}

// ---------------- CSR build (+ fused W->bf16 transpose prep) ----------------
__global__ void k_deg_prep(const int* __restrict__ ei, int E, int ET, int* __restrict__ deg,
                           const float* __restrict__ Wl1, const float* __restrict__ Wr1,
                           const float* __restrict__ Wl2, const float* __restrict__ Wr2,
                           unsigned short* __restrict__ wt1l, unsigned short* __restrict__ wt1r,
                           unsigned short* __restrict__ wt2l, unsigned short* __restrict__ wt2r,
                           int egrid) {
  int b = blockIdx.x;
  if (b < egrid) {
    int e = b * TPB + threadIdx.x;
    if (e < ET) {
      int dst = (e < E) ? ei[E + e] : (e - E);
      atomicAdd(&deg[dst], 1);
    }
  } else {
    int i = (b - egrid) * TPB + threadIdx.x;
    if (i < 32768) {
      int c = i >> 7, k = i & 127;
      wt1l[i] = f2bf(Wl1[(size_t)k * 256 + c]);
    } else if (i < 65536) {
      int j = i - 32768; int c = j >> 7, k = j & 127;
      wt1r[j] = f2bf(Wr1[(size_t)k * 256 + c]);
    } else if (i < 69632) {
      int j = i - 65536; int c = j >> 6, k = j & 63;
      wt2l[j] = f2bf(Wl2[(size_t)k * 64 + c]);
    } else if (i < 73728) {
      int j = i - 69632; int c = j >> 6, k = j & 63;
      wt2r[j] = f2bf(Wr2[(size_t)k * 64 + c]);
    }
  }
}

__global__ void k_scan1(const int* __restrict__ deg, int N, int* __restrict__ bsum) {
  __shared__ int sm[TPB];
  int i = blockIdx.x * TPB + threadIdx.x;
  sm[threadIdx.x] = (i < N) ? ((deg[i] + 3) & ~3) : 0;  // padded degrees
  __syncthreads();
  for (int d = TPB / 2; d > 0; d >>= 1) {
    if (threadIdx.x < d) sm[threadIdx.x] += sm[threadIdx.x + d];
    __syncthreads();
  }
  if (threadIdx.x == 0) bsum[blockIdx.x] = sm[0];
}

// requires SB <= TPB (N <= 65536). Offsets are 4-aligned (padded degrees).
__global__ void k_scan3(const int* __restrict__ deg, const int* __restrict__ bsum,
                        int SB, int N, int* __restrict__ rowoff, int* __restrict__ cursor) {
  __shared__ int sm[TPB];
  int pv = (threadIdx.x < blockIdx.x) ? bsum[threadIdx.x] : 0;
  sm[threadIdx.x] = pv;
  __syncthreads();
  for (int dd = TPB / 2; dd > 0; dd >>= 1) {
    if (threadIdx.x < dd) sm[threadIdx.x] += sm[threadIdx.x + dd];
    __syncthreads();
  }
  int base = sm[0];
  __syncthreads();
  int i = blockIdx.x * TPB + threadIdx.x;
  int v = (i < N) ? ((deg[i] + 3) & ~3) : 0;
  sm[threadIdx.x] = v;
  __syncthreads();
  for (int dd = 1; dd < TPB; dd <<= 1) {
    int t = (threadIdx.x >= dd) ? sm[threadIdx.x - dd] : 0;
    __syncthreads();
    sm[threadIdx.x] += t;
    __syncthreads();
  }
  if (i < N) {
    int off = base + sm[threadIdx.x] - v;  // exclusive, 4-aligned
    rowoff[i] = off;
    cursor[i] = off;
  }
}

__global__ void k_fill(const int* __restrict__ ei, int E, int ET,
                       int* __restrict__ cursor, int* __restrict__ csrc) {
  int e = blockIdx.x * blockDim.x + threadIdx.x;
  if (e >= ET) return;
  int src, dst;
  if (e < E) { src = ei[e]; dst = ei[E + e]; } else { src = dst = e - E; }
  int pos = atomicAdd(&cursor[dst], 1);
  csrc[pos] = src;
}

// ---------------- MFMA GEMM: out{0,1}_bf16 = act(A_f32) @ Wt{0,1}^T + b{0,1} ----------------
// A [M,K] f32 (optional BN-affine+relu), Wt pre-transposed [Nc][K] bf16.
// Column tiles looped inside the block: A staged once. LDS XOR-swizzled.
__global__ void k_gemm_mfma(const float* __restrict__ A, const float* __restrict__ affine,
                            const unsigned short* __restrict__ Wt0, const float* __restrict__ b0,
                            const unsigned short* __restrict__ Wt1, const float* __restrict__ b1,
                            unsigned short* __restrict__ out0, unsigned short* __restrict__ out1,
                            int M, int K, int Nc) {
  extern __shared__ short lds[];
  short* As = lds;
  short* Bls = lds + 64 * K;
  short* Brs = lds + 128 * K;
  const int r0 = blockIdx.x * 64;
  const int tid = threadIdx.x;
  const int Kb = K * 2;
  const int w = tid >> 6, lane = tid & 63;
  const int arow = w * 16 + (lane & 15);
  const int l16 = (lane >> 4) << 3;
  const int rbase0 = r0 + w * 16 + ((lane >> 4) << 2);

  // ---- stage A once: f32 (+optional affine+relu) -> bf16, swizzled ----
  const int fpr = K >> 2;  // float4 per row
  for (int idx = tid; idx < 64 * fpr; idx += TPB) {
    int row = idx / fpr, c4 = idx - row * fpr;
    int gr = r0 + row;
    float4 v = make_float4(0.f, 0.f, 0.f, 0.f);
    if (gr < M) v = *(const float4*)(A + (size_t)gr * K + c4 * 4);
    if (affine) {
      int c = c4 * 4;
      v.x = fmaxf(v.x * affine[c + 0] + affine[64 + c + 0], 0.f);
      v.y = fmaxf(v.y * affine[c + 1] + affine[64 + c + 1], 0.f);
      v.z = fmaxf(v.z * affine[c + 2] + affine[64 + c + 2], 0.f);
      v.w = fmaxf(v.w * affine[c + 3] + affine[64 + c + 3], 0.f);
    }
    ushort4 pk; pk.x = f2bf(v.x); pk.y = f2bf(v.y); pk.z = f2bf(v.z); pk.w = f2bf(v.w);
    int kb = (c4 * 8) ^ ((row & 7) << 4);
    *(ushort4*)((char*)As + row * Kb + kb) = pk;
  }

  const int cpr = K >> 3;  // uint4 chunks per col
  for (int nt = 0; nt < Nc; nt += 64) {
    __syncthreads();  // waves done reading previous W tile (and A staged on first iter)
    for (int idx = tid; idx < 64 * cpr; idx += TPB) {
      int c = idx / cpr, k8 = (idx - c * cpr) * 8;
      int kb = (k8 * 2) ^ ((c & 7) << 4);
      uint4 w0 = *(const uint4*)(Wt0 + (size_t)(nt + c) * K + k8);
      *(uint4*)((char*)Bls + c * Kb + kb) = w0;
      uint4 w1 = *(const uint4*)(Wt1 + (size_t)(nt + c) * K + k8);
      *(uint4*)((char*)Brs + c * Kb + kb) = w1;
    }
    __syncthreads();

    f32x4 accL[4], accR[4];
#pragma unroll
    for (int i = 0; i < 4; ++i) { accL[i] = (f32x4)0.f; accR[i] = (f32x4)0.f; }
    for (int k0 = 0; k0 < K; k0 += 32) {
      int kb = (k0 + l16) * 2;
      bfrag8 af = *(bfrag8*)((char*)As + arow * Kb + (kb ^ ((arow & 7) << 4)));
#pragma unroll
      for (int cf = 0; cf < 4; ++cf) {
        int col = cf * 16 + (lane & 15);
        int cb = col * Kb + (kb ^ ((col & 7) << 4));
        bfrag8 bl = *(bfrag8*)((char*)Bls + cb);
        accL[cf] = __builtin_amdgcn_mfma_f32_16x16x32_bf16(af, bl, accL[cf], 0, 0, 0);
        bfrag8 br = *(bfrag8*)((char*)Brs + cb);
        accR[cf] = __builtin_amdgcn_mfma_f32_16x16x32_bf16(af, br, accR[cf], 0, 0, 0);
      }
    }
    // epilogue: C/D map col=lane&15, row=(lane>>4)*4+reg
    const int cbase = nt + (lane & 15);
#pragma unroll
    for (int cf = 0; cf < 4; ++cf) {
      int gcol = cbase + cf * 16;
      float bb0 = b0[gcol], bb1 = b1[gcol];
#pragma unroll
      for (int r = 0; r < 4; ++r) {
        int grow = rbase0 + r;
        if (grow < M) {
          out0[(size_t)grow * Nc + gcol] = f2bf(accL[cf][r] + bb0);
          out1[(size_t)grow * Nc + gcol] = f2bf(accR[cf][r] + bb1);
        }
      }
    }
  }
}

// ---------------- GATv2 layer 1: H=4, C=64; one node/wave; 4-edge aligned quads ----------------
__global__ __launch_bounds__(TPB) void k_gat1(
    const unsigned short* __restrict__ xl, const unsigned short* __restrict__ xr,
    const int* __restrict__ rowoff, const int* __restrict__ deg,
    const int* __restrict__ csrc,
    const float* __restrict__ att, const float* __restrict__ bias,
    float* __restrict__ out, int N) {
  int node = (blockIdx.x * TPB + threadIdx.x) >> 6;
  int lane = threadIdx.x & 63;
  if (node >= N) return;
  int l4 = lane * 4;
  float4 atv = *(const float4*)(att + l4);
  float4 bb = *(const float4*)(bias + l4);
  uint2 rv = *(const uint2*)(xr + (node << 8) + l4);
  float xr0 = bf2f(rv.x & 0xffffu), xr1 = bf2f(rv.x >> 16);
  float xr2 = bf2f(rv.y & 0xffffu), xr3 = bf2f(rv.y >> 16);
  int beg = rowoff[node];
  int dg = deg[node];
  int endR = beg + dg;          // real end
  int endF = beg + (dg & ~3);   // full quads
  float s = 0.f, a0 = 0.f, a1 = 0.f, a2 = 0.f, a3 = 0.f;
  int k = beg;
  for (; k < endF; k += 4) {
    int4 q = *(const int4*)(csrc + k);  // 4-aligned (padded rows)
    uint2 vv[4];
    vv[0] = *(const uint2*)(xl + (q.x << 8) + l4);
    vv[1] = *(const uint2*)(xl + (q.y << 8) + l4);
    vv[2] = *(const uint2*)(xl + (q.z << 8) + l4);
    vv[3] = *(const uint2*)(xl + (q.w << 8) + l4);
    float xs[4][4], ps[4];
#pragma unroll
    for (int u = 0; u < 4; ++u) {
      xs[u][0] = bf2f(vv[u].x & 0xffffu); xs[u][1] = bf2f(vv[u].x >> 16);
      xs[u][2] = bf2f(vv[u].y & 0xffffu); xs[u][3] = bf2f(vv[u].y >> 16);
      float t0 = xs[u][0] + xr0, t1 = xs[u][1] + xr1;
      float t2 = xs[u][2] + xr2, t3 = xs[u][3] + xr3;
      ps[u] = fmaxf(t0, 0.2f * t0) * atv.x + fmaxf(t1, 0.2f * t1) * atv.y
            + fmaxf(t2, 0.2f * t2) * atv.z + fmaxf(t3, 0.2f * t3) * atv.w;
    }
#pragma unroll
    for (int u = 0; u < 4; ++u) ps[u] = red16(ps[u]);
#pragma unroll
    for (int u = 0; u < 4; ++u) {
      float wv = __expf(ps[u]);
      s += wv;
      a0 += wv * xs[u][0]; a1 += wv * xs[u][1];
      a2 += wv * xs[u][2]; a3 += wv * xs[u][3];
    }
  }
  if (k < endR) {  // one predicated aligned quad (padding srcs are 0 -> valid row)
    int4 q = *(const int4*)(csrc + k);
    uint2 vv[4];
    vv[0] = *(const uint2*)(xl + (q.x << 8) + l4);
    vv[1] = *(const uint2*)(xl + (q.y << 8) + l4);
    vv[2] = *(const uint2*)(xl + (q.z << 8) + l4);
    vv[3] = *(const uint2*)(xl + (q.w << 8) + l4);
    float xs[4][4], ps[4];
#pragma unroll
    for (int u = 0; u < 4; ++u) {
      xs[u][0] = bf2f(vv[u].x & 0xffffu); xs[u][1] = bf2f(vv[u].x >> 16);
      xs[u][2] = bf2f(vv[u].y & 0xffffu); xs[u][3] = bf2f(vv[u].y >> 16);
      float t0 = xs[u][0] + xr0, t1 = xs[u][1] + xr1;
      float t2 = xs[u][2] + xr2, t3 = xs[u][3] + xr3;
      ps[u] = fmaxf(t0, 0.2f * t0) * atv.x + fmaxf(t1, 0.2f * t1) * atv.y
            + fmaxf(t2, 0.2f * t2) * atv.z + fmaxf(t3, 0.2f * t3) * atv.w;
    }
#pragma unroll
    for (int u = 0; u < 4; ++u) ps[u] = red16(ps[u]);
#pragma unroll
    for (int u = 0; u < 4; ++u) {
      float wv = (k + u < endR) ? __expf(ps[u]) : 0.f;
      s += wv;
      a0 += wv * xs[u][0]; a1 += wv * xs[u][1];
      a2 += wv * xs[u][2]; a3 += wv * xs[u][3];
    }
  }
  float inv = 1.f / (s + 1e-16f);
  a0 *= inv; a1 *= inv; a2 *= inv; a3 *= inv;
  // mean over the 4 heads
  a0 += __shfl_xor(a0, 16); a0 += __shfl_xor(a0, 32);
  a1 += __shfl_xor(a1, 16); a1 += __shfl_xor(a1, 32);
  a2 += __shfl_xor(a2, 16); a2 += __shfl_xor(a2, 32);
  a3 += __shfl_xor(a3, 16); a3 += __shfl_xor(a3, 32);
  if (lane < 16) {
    float4 o;
    o.x = a0 * 0.25f + bb.x;
    o.y = a1 * 0.25f + bb.y;
    o.z = a2 * 0.25f + bb.z;
    o.w = a3 * 0.25f + bb.w;
    *(float4*)(out + (node << 6) + l4) = o;
  }
}

// ---------------- GATv2 layer 2: H=1, C=64; 4 edges/wave (16 lanes each) ----------------
__global__ __launch_bounds__(TPB) void k_gat2(
    const unsigned short* __restrict__ xl, const unsigned short* __restrict__ xr,
    const int* __restrict__ rowoff, const int* __restrict__ deg,
    const int* __restrict__ csrc,
    const float* __restrict__ att, const float* __restrict__ bias,
    float* __restrict__ out, int N) {
  int node = (blockIdx.x * TPB + threadIdx.x) >> 6;
  int lane = threadIdx.x & 63;
  if (node >= N) return;
  int grp = lane >> 4, c4 = (lane & 15) * 4;
  float4 atv = *(const float4*)(att + c4);
  float4 bb = *(const float4*)(bias + c4);
  uint2 rv = *(const uint2*)(xr + (node << 6) + c4);
  float xr0 = bf2f(rv.x & 0xffffu), xr1 = bf2f(rv.x >> 16);
  float xr2 = bf2f(rv.y & 0xffffu), xr3 = bf2f(rv.y >> 16);
  int beg = rowoff[node];
  int dg = deg[node];
  int endR = beg + dg;
  int quads = (dg + 3) >> 2;  // padded rows -> safe aligned reads
  float s = 0.f, a0 = 0.f, a1 = 0.f, a2 = 0.f, a3 = 0.f;
  for (int it = 0; it < quads; ++it) {
    int kk = beg + it * 4 + grp;
    int src = csrc[kk];                 // padding reads src=0 (valid row)
    bool ok = kk < endR;
    uint2 v = *(const uint2*)(xl + (src << 6) + c4);
    float x0 = bf2f(v.x & 0xffffu), x1 = bf2f(v.x >> 16);
    float x2 = bf2f(v.y & 0xffffu), x3 = bf2f(v.y >> 16);
    float t0 = x0 + xr0, t1 = x1 + xr1, t2 = x2 + xr2, t3 = x3 + xr3;
    float p = fmaxf(t0, 0.2f * t0) * atv.x + fmaxf(t1, 0.2f * t1) * atv.y
            + fmaxf(t2, 0.2f * t2) * atv.z + fmaxf(t3, 0.2f * t3) * atv.w;
    p = red16(p);
    float wv = ok ? __expf(p) : 0.f;
    s += wv;
    a0 += wv * x0; a1 += wv * x1; a2 += wv * x2; a3 += wv * x3;
  }
  // sum the 4 edge-groups
  s += __shfl_xor(s, 16); s += __shfl_xor(s, 32);
  a0 += __shfl_xor(a0, 16); a0 += __shfl_xor(a0, 32);
  a1 += __shfl_xor(a1, 16); a1 += __shfl_xor(a1, 32);
  a2 += __shfl_xor(a2, 16); a2 += __shfl_xor(a2, 32);
  a3 += __shfl_xor(a3, 16); a3 += __shfl_xor(a3, 32);
  if (lane < 16) {
    float inv = 1.f / (s + 1e-16f);
    float4 o;
    o.x = a0 * inv + bb.x;
    o.y = a1 * inv + bb.y;
    o.z = a2 * inv + bb.z;
    o.w = a3 * inv + bb.w;
    *(float4*)(out + (node << 6) + c4) = o;
  }
}

// ---------------- BatchNorm ----------------
__global__ void k_bnstat(const float* __restrict__ in, int N, float* __restrict__ part) {
  __shared__ float sm[TPB], sq[TPB];
  int col = threadIdx.x & 63;
  int rq = threadIdx.x >> 6;
  float s = 0.f, q = 0.f;
  for (int r = blockIdx.x * 4 + rq; r < N; r += gridDim.x * 4) {
    float v = in[(size_t)r * 64 + col];
    s += v; q += v * v;
  }
  sm[threadIdx.x] = s; sq[threadIdx.x] = q;
  __syncthreads();
  if (threadIdx.x < 64) {
    s = sm[threadIdx.x] + sm[threadIdx.x + 64] + sm[threadIdx.x + 128] + sm[threadIdx.x + 192];
    q = sq[threadIdx.x] + sq[threadIdx.x + 64] + sq[threadIdx.x + 128] + sq[threadIdx.x + 192];
    part[(size_t)blockIdx.x * 128 + threadIdx.x] = s;
    part[(size_t)blockIdx.x * 128 + 64 + threadIdx.x] = q;
  }
}

__global__ void k_bnfin(const float* __restrict__ part, int B, int N,
                        const float* __restrict__ g, const float* __restrict__ beta,
                        float* __restrict__ ab) {
  int c = threadIdx.x;  // 64 threads
  float s = 0.f, q = 0.f;
  for (int b = 0; b < B; ++b) {
    s += part[(size_t)b * 128 + c];
    q += part[(size_t)b * 128 + 64 + c];
  }
  float mean = s / (float)N;
  float var = q / (float)N - mean * mean;
  float a = g[c] * rsqrtf(var + 1e-5f);
  ab[c] = a;
  ab[64 + c] = beta[c] - mean * a;
}

__global__ void k_bnapply(const float* __restrict__ in, const float* __restrict__ ab,
                          float* __restrict__ out, int total4) {
  int idx = blockIdx.x * blockDim.x + threadIdx.x;
  if (idx >= total4) return;
  float4 v = *(const float4*)(in + (size_t)idx * 4);
  int c0 = (idx & 15) * 4;
  v.x = fmaxf(v.x * ab[c0 + 0] + ab[64 + c0 + 0], 0.f);
  v.y = fmaxf(v.y * ab[c0 + 1] + ab[64 + c0 + 1], 0.f);
  v.z = fmaxf(v.z * ab[c0 + 2] + ab[64 + c0 + 2], 0.f);
  v.w = fmaxf(v.w * ab[c0 + 3] + ab[64 + c0 + 3], 0.f);
  *(float4*)(out + (size_t)idx * 4) = v;
}

extern "C" void kernel_launch(void* const* d_in, const int* in_sizes, int n_in,
                              void* d_out, int out_size, void* d_ws, size_t ws_size,
                              hipStream_t stream) {
  const float* x     = (const float*)d_in[0];
  const int*   ei    = (const int*)d_in[1];
  const float* Wl1   = (const float*)d_in[2];
  const float* bl1   = (const float*)d_in[3];
  const float* Wr1   = (const float*)d_in[4];
  const float* br1   = (const float*)d_in[5];
  const float* att1  = (const float*)d_in[6];
  const float* bias1 = (const float*)d_in[7];
  const float* g1    = (const float*)d_in[8];
  const float* be1   = (const float*)d_in[9];
  const float* Wl2   = (const float*)d_in[10];
  const float* bl2   = (const float*)d_in[11];
  const float* Wr2   = (const float*)d_in[12];
  const float* br2   = (const float*)d_in[13];
  const float* att2  = (const float*)d_in[14];
  const float* bias2 = (const float*)d_in[15];
  const float* g2    = (const float*)d_in[16];
  const float* be2   = (const float*)d_in[17];
  float* out = (float*)d_out;

  const int N  = in_sizes[0] / 128;   // 50000
  const int E  = in_sizes[1] / 2;     // 800000
  const int ET = E + N;
  const int ETP = ET + 4 * ((N + 255) & ~255);  // padded-CSR upper bound (deg+3 per node)
  const int SB = (N + TPB - 1) / TPB; // 196 (<= TPB required)

  char* p = (char*)d_ws;
  auto take = [&](size_t b) { char* q = p; p += (b + 255) & ~(size_t)255; return q; };

  unsigned short* xl1 = (unsigned short*)take((size_t)N * 256 * 2);
  unsigned short* xr1 = (unsigned short*)take((size_t)N * 256 * 2);
  unsigned short* xl2 = (unsigned short*)take((size_t)N * 64 * 2);
  unsigned short* xr2 = (unsigned short*)take((size_t)N * 64 * 2);
  float* out1 = (float*)take((size_t)N * 64 * 4);
  unsigned short* wt1l = (unsigned short*)take(256 * 128 * 2);
  unsigned short* wt1r = (unsigned short*)take(256 * 128 * 2);
  unsigned short* wt2l = (unsigned short*)take(64 * 64 * 2);
  unsigned short* wt2r = (unsigned short*)take(64 * 64 * 2);
  // deg and csrc adjacent -> one memset covers both (deg zeros + csrc padding zeros)
  int* deg    = (int*)take((size_t)N * 4);
  int* csrc   = (int*)take((size_t)ETP * 4 + 16);
  size_t zero_bytes = (char*)(csrc + ETP) + 16 - (char*)deg;
  int* rowoff = (int*)take((size_t)(N + 1) * 4);
  int* cursor = (int*)take((size_t)N * 4);
  int* bsum   = (int*)take((size_t)SB * 4);
  float* part = (float*)take((size_t)256 * 128 * 4);
  float* ab1  = (float*)take(128 * 4);
  float* ab2  = (float*)take(128 * 4);
  (void)ws_size; (void)n_in; (void)out_size;

  int egrid = (ET + TPB - 1) / TPB;
  int wgrid = (73728 + TPB - 1) / TPB;  // W-conversion blocks
  int ngrid = (N + 3) / 4;              // one node per wave, 4 waves/block
  int mtile = (N + 63) / 64;            // 782
  int total4 = N * 16;

  // CSR build (padded rows) + W prep fused
  hipMemsetAsync(deg, 0, zero_bytes, stream);
  k_deg_prep<<<egrid + wgrid, TPB, 0, stream>>>(ei, E, ET, deg,
                                                Wl1, Wr1, Wl2, Wr2,
                                                wt1l, wt1r, wt2l, wt2r, egrid);
  k_scan1<<<SB, TPB, 0, stream>>>(deg, N, bsum);
  k_scan3<<<SB, TPB, 0, stream>>>(deg, bsum, SB, N, rowoff, cursor);
  k_fill<<<egrid, TPB, 0, stream>>>(ei, E, ET, cursor, csrc);

  // Layer 1: GEMM stages A from f32 x directly (no affine)
  k_gemm_mfma<<<mtile, TPB, 3 * 64 * 128 * 2, stream>>>(
      x, nullptr, wt1l, bl1, wt1r, br1, xl1, xr1, N, 128, 256);
  k_gat1<<<ngrid, TPB, 0, stream>>>(xl1, xr1, rowoff, deg, csrc, att1, bias1, out1, N);
  k_bnstat<<<256, TPB, 0, stream>>>(out1, N, part);
  k_bnfin<<<1, 64, 0, stream>>>(part, 256, N, g1, be1, ab1);

  // Layer 2: BN affine + relu fused into GEMM A-staging
  k_gemm_mfma<<<mtile, TPB, 3 * 64 * 64 * 2, stream>>>(
      out1, ab1, wt2l, bl2, wt2r, br2, xl2, xr2, N, 64, 64);
  k_gat2<<<ngrid, TPB, 0, stream>>>(xl2, xr2, rowoff, deg, csrc, att2, bias2, out, N);
  k_bnstat<<<256, TPB, 0, stream>>>(out, N, part);
  k_bnfin<<<1, 64, 0, stream>>>(part, 256, N, g2, be2, ab2);
  k_bnapply<<<(total4 + TPB - 1) / TPB, TPB, 0, stream>>>(out, ab2, out, total4);
}

// Round 7
// 414.043 us; speedup vs baseline: 1.0231x; 1.0231x over previous
//
#include <hip/hip_runtime.h>
#include <hip/hip_bf16.h>
#include <math.h>

#define TPB 256

typedef __attribute__((ext_vector_type(8))) _Float16 hfrag8;
typedef __attribute__((ext_vector_type(2))) _Float16 h2;
typedef __attribute__((ext_vector_type(4))) float f32x4;

union HU { unsigned int u; h2 h; };

static __device__ __forceinline__ h2 as_h2(unsigned int u) { HU c; c.u = u; return c.h; }
static __device__ __forceinline__ unsigned short f2h_bits(float f) {
  union { _Float16 h; unsigned short s; } c; c.h = (_Float16)f; return c.s;
}

// DPP row-rotate ring reduction within each 16-lane row.
#define DPP_ROR(v, C) __int_as_float(__builtin_amdgcn_update_dpp( \
    __float_as_int(v), __float_as_int(v), (C), 0xf, 0xf, false))
static __device__ __forceinline__ float red16(float p) {
  p += DPP_ROR(p, 0x121);  // row_ror:1
  p += DPP_ROR(p, 0x122);  // row_ror:2
  p += DPP_ROR(p, 0x124);  // row_ror:4
  p += DPP_ROR(p, 0x128);  // row_ror:8
  return p;
}

// ---------------- fused prep: degrees + x->f16 + W->f16 transposed ----------------
__global__ void k_prep_all(const int* __restrict__ ei, int E, int ET, int* __restrict__ deg,
                           const float* __restrict__ x,
                           const float* __restrict__ Wl1, const float* __restrict__ Wr1,
                           const float* __restrict__ Wl2, const float* __restrict__ Wr2,
                           unsigned short* __restrict__ xb,
                           unsigned short* __restrict__ wt1l, unsigned short* __restrict__ wt1r,
                           unsigned short* __restrict__ wt2l, unsigned short* __restrict__ wt2r,
                           int nx4) {
  int i = blockIdx.x * TPB + threadIdx.x;
  if (i < ET) {
    int dst = (i < E) ? ei[E + i] : (i - E);
    atomicAdd(&deg[dst], 1);
    return;
  }
  i -= ET;
  if (i < nx4) {
    float4 v = *(const float4*)(x + (size_t)i * 4);
    ushort4 o;
    o.x = f2h_bits(v.x); o.y = f2h_bits(v.y); o.z = f2h_bits(v.z); o.w = f2h_bits(v.w);
    *(ushort4*)(xb + (size_t)i * 4) = o;
    return;
  }
  i -= nx4;
  if (i < 32768) {
    int c = i >> 7, k = i & 127;
    wt1l[i] = f2h_bits(Wl1[(size_t)k * 256 + c]);
  } else if (i < 65536) {
    int j = i - 32768; int c = j >> 7, k = j & 127;
    wt1r[j] = f2h_bits(Wr1[(size_t)k * 256 + c]);
  } else if (i < 69632) {
    int j = i - 65536; int c = j >> 6, k = j & 63;
    wt2l[j] = f2h_bits(Wl2[(size_t)k * 64 + c]);
  } else if (i < 73728) {
    int j = i - 69632; int c = j >> 6, k = j & 63;
    wt2r[j] = f2h_bits(Wr2[(size_t)k * 64 + c]);
  }
}

__global__ void k_scan1(const int* __restrict__ deg, int N, int* __restrict__ bsum) {
  __shared__ int sm[TPB];
  int i = blockIdx.x * TPB + threadIdx.x;
  sm[threadIdx.x] = (i < N) ? ((deg[i] + 3) & ~3) : 0;  // padded degrees
  __syncthreads();
  for (int d = TPB / 2; d > 0; d >>= 1) {
    if (threadIdx.x < d) sm[threadIdx.x] += sm[threadIdx.x + d];
    __syncthreads();
  }
  if (threadIdx.x == 0) bsum[blockIdx.x] = sm[0];
}

// requires SB <= TPB (N <= 65536). Offsets are 4-aligned (padded degrees).
__global__ void k_scan3(const int* __restrict__ deg, const int* __restrict__ bsum,
                        int SB, int N, int* __restrict__ rowoff, int* __restrict__ cursor) {
  __shared__ int sm[TPB];
  int pv = (threadIdx.x < blockIdx.x) ? bsum[threadIdx.x] : 0;
  sm[threadIdx.x] = pv;
  __syncthreads();
  for (int dd = TPB / 2; dd > 0; dd >>= 1) {
    if (threadIdx.x < dd) sm[threadIdx.x] += sm[threadIdx.x + dd];
    __syncthreads();
  }
  int base = sm[0];
  __syncthreads();
  int i = blockIdx.x * TPB + threadIdx.x;
  int v = (i < N) ? ((deg[i] + 3) & ~3) : 0;
  sm[threadIdx.x] = v;
  __syncthreads();
  for (int dd = 1; dd < TPB; dd <<= 1) {
    int t = (threadIdx.x >= dd) ? sm[threadIdx.x - dd] : 0;
    __syncthreads();
    sm[threadIdx.x] += t;
    __syncthreads();
  }
  if (i < N) {
    int off = base + sm[threadIdx.x] - v;  // exclusive, 4-aligned
    rowoff[i] = off;
    cursor[i] = off;
  }
}

__global__ void k_fill(const int* __restrict__ ei, int E, int ET,
                       int* __restrict__ cursor, int* __restrict__ csrc) {
  int e = blockIdx.x * blockDim.x + threadIdx.x;
  if (e >= ET) return;
  int src, dst;
  if (e < E) { src = ei[e]; dst = ei[E + e]; } else { src = dst = e - E; }
  int pos = atomicAdd(&cursor[dst], 1);
  csrc[pos] = src;
}

// ---------------- MFMA GEMM (f16 in): out{0,1}_f16 = Ab @ Wt{0,1}^T + b{0,1} ----------------
// LDS XOR-swizzled. Wt pre-transposed [Nc][K] f16.
__global__ void k_gemm_mfma(const unsigned short* __restrict__ Ab,
                            const unsigned short* __restrict__ Wt0, const float* __restrict__ b0,
                            const unsigned short* __restrict__ Wt1, const float* __restrict__ b1,
                            unsigned short* __restrict__ out0, unsigned short* __restrict__ out1,
                            int M, int K, int Nc) {
  extern __shared__ short lds[];
  short* As = lds;
  short* Bls = lds + 64 * K;
  short* Brs = lds + 128 * K;
  const int r0 = blockIdx.x * 64, n0 = blockIdx.y * 64;
  const int tid = threadIdx.x;
  const int Kb = K * 2;
  const int cpr = K >> 3;          // 16B chunks per row
  const int chunks = 64 * cpr;
  for (int idx = tid; idx < chunks; idx += TPB) {
    int row = idx / cpr, k8 = (idx - row * cpr) * 8;
    int kb = (k8 * 2) ^ ((row & 7) << 4);
    int gr = r0 + row;
    uint4 av = make_uint4(0, 0, 0, 0);
    if (gr < M) av = *(const uint4*)(Ab + (size_t)gr * K + k8);
    *(uint4*)((char*)As + row * Kb + kb) = av;
    uint4 w0 = *(const uint4*)(Wt0 + (size_t)(n0 + row) * K + k8);
    *(uint4*)((char*)Bls + row * Kb + kb) = w0;
    uint4 w1 = *(const uint4*)(Wt1 + (size_t)(n0 + row) * K + k8);
    *(uint4*)((char*)Brs + row * Kb + kb) = w1;
  }
  __syncthreads();

  const int w = tid >> 6, lane = tid & 63;
  const int arow = w * 16 + (lane & 15);
  const int l16 = (lane >> 4) << 3;
  f32x4 accL[4], accR[4];
#pragma unroll
  for (int i = 0; i < 4; ++i) { accL[i] = (f32x4)0.f; accR[i] = (f32x4)0.f; }
  for (int k0 = 0; k0 < K; k0 += 32) {
    int kb = (k0 + l16) * 2;
    hfrag8 af = *(hfrag8*)((char*)As + arow * Kb + (kb ^ ((arow & 7) << 4)));
#pragma unroll
    for (int cf = 0; cf < 4; ++cf) {
      int col = cf * 16 + (lane & 15);
      int cb = col * Kb + (kb ^ ((col & 7) << 4));
      hfrag8 bl = *(hfrag8*)((char*)Bls + cb);
      accL[cf] = __builtin_amdgcn_mfma_f32_16x16x32_f16(af, bl, accL[cf], 0, 0, 0);
      hfrag8 br = *(hfrag8*)((char*)Brs + cb);
      accR[cf] = __builtin_amdgcn_mfma_f32_16x16x32_f16(af, br, accR[cf], 0, 0, 0);
    }
  }
  // epilogue: C/D map col=lane&15, row=(lane>>4)*4+reg
  const int rbase = r0 + w * 16 + ((lane >> 4) << 2);
  const int cbase = n0 + (lane & 15);
#pragma unroll
  for (int cf = 0; cf < 4; ++cf) {
    int gcol = cbase + cf * 16;
    float bb0 = b0[gcol], bb1 = b1[gcol];
#pragma unroll
    for (int r = 0; r < 4; ++r) {
      int grow = rbase + r;
      if (grow < M) {
        out0[(size_t)grow * Nc + gcol] = f2h_bits(accL[cf][r] + bb0);
        out1[(size_t)grow * Nc + gcol] = f2h_bits(accR[cf][r] + bb1);
      }
    }
  }
}

// ---------------- GATv2 layer 1: H=4, C=64; one node/wave; f16 packed math ----------------
__global__ __launch_bounds__(TPB) void k_gat1(
    const unsigned short* __restrict__ xl, const unsigned short* __restrict__ xr,
    const int* __restrict__ rowoff, const int* __restrict__ deg,
    const int* __restrict__ csrc,
    const float* __restrict__ att, const float* __restrict__ bias,
    float* __restrict__ out, int N) {
  int node = (blockIdx.x * TPB + threadIdx.x) >> 6;
  int lane = threadIdx.x & 63;
  if (node >= N) return;
  int l4 = lane * 4;
  float4 atv = *(const float4*)(att + l4);
  h2 at01, at23;
  at01.x = (_Float16)atv.x; at01.y = (_Float16)atv.y;
  at23.x = (_Float16)atv.z; at23.y = (_Float16)atv.w;
  float4 bb = *(const float4*)(bias + l4);
  uint2 rv = *(const uint2*)(xr + (node << 8) + l4);
  h2 xr01 = as_h2(rv.x), xr23 = as_h2(rv.y);
  const _Float16 c02 = (_Float16)0.2f;
  int beg = rowoff[node];
  int dg = deg[node];
  int endR = beg + dg;          // real end
  int endF = beg + (dg & ~3);   // full quads
  float s = 0.f, a0 = 0.f, a1 = 0.f, a2 = 0.f, a3 = 0.f;
  int k = beg;
  for (; k < endF; k += 4) {
    int4 q = *(const int4*)(csrc + k);  // 4-aligned (padded rows)
    uint2 vv[4];
    vv[0] = *(const uint2*)(xl + (q.x << 8) + l4);
    vv[1] = *(const uint2*)(xl + (q.y << 8) + l4);
    vv[2] = *(const uint2*)(xl + (q.z << 8) + l4);
    vv[3] = *(const uint2*)(xl + (q.w << 8) + l4);
    float ps[4];
#pragma unroll
    for (int u = 0; u < 4; ++u) {
      h2 x01 = as_h2(vv[u].x), x23 = as_h2(vv[u].y);
      h2 t01 = x01 + xr01, t23 = x23 + xr23;
      h2 l01 = __builtin_elementwise_max(t01, t01 * c02);
      h2 l23 = __builtin_elementwise_max(t23, t23 * c02);
      ps[u] = __builtin_amdgcn_fdot2(l01, at01,
              __builtin_amdgcn_fdot2(l23, at23, 0.f, false), false);
    }
#pragma unroll
    for (int u = 0; u < 4; ++u) ps[u] = red16(ps[u]);
#pragma unroll
    for (int u = 0; u < 4; ++u) {
      float wv = __expf(ps[u]);
      h2 x01 = as_h2(vv[u].x), x23 = as_h2(vv[u].y);
      s += wv;
      a0 += wv * (float)x01.x; a1 += wv * (float)x01.y;
      a2 += wv * (float)x23.x; a3 += wv * (float)x23.y;
    }
  }
  if (k < endR) {  // one predicated aligned quad (padding srcs are 0 -> valid row)
    int4 q = *(const int4*)(csrc + k);
    uint2 vv[4];
    vv[0] = *(const uint2*)(xl + (q.x << 8) + l4);
    vv[1] = *(const uint2*)(xl + (q.y << 8) + l4);
    vv[2] = *(const uint2*)(xl + (q.z << 8) + l4);
    vv[3] = *(const uint2*)(xl + (q.w << 8) + l4);
    float ps[4];
#pragma unroll
    for (int u = 0; u < 4; ++u) {
      h2 x01 = as_h2(vv[u].x), x23 = as_h2(vv[u].y);
      h2 t01 = x01 + xr01, t23 = x23 + xr23;
      h2 l01 = __builtin_elementwise_max(t01, t01 * c02);
      h2 l23 = __builtin_elementwise_max(t23, t23 * c02);
      ps[u] = __builtin_amdgcn_fdot2(l01, at01,
              __builtin_amdgcn_fdot2(l23, at23, 0.f, false), false);
    }
#pragma unroll
    for (int u = 0; u < 4; ++u) ps[u] = red16(ps[u]);
#pragma unroll
    for (int u = 0; u < 4; ++u) {
      float wv = (k + u < endR) ? __expf(ps[u]) : 0.f;
      h2 x01 = as_h2(vv[u].x), x23 = as_h2(vv[u].y);
      s += wv;
      a0 += wv * (float)x01.x; a1 += wv * (float)x01.y;
      a2 += wv * (float)x23.x; a3 += wv * (float)x23.y;
    }
  }
  float inv = 1.f / (s + 1e-16f);
  a0 *= inv; a1 *= inv; a2 *= inv; a3 *= inv;
  // mean over the 4 heads
  a0 += __shfl_xor(a0, 16); a0 += __shfl_xor(a0, 32);
  a1 += __shfl_xor(a1, 16); a1 += __shfl_xor(a1, 32);
  a2 += __shfl_xor(a2, 16); a2 += __shfl_xor(a2, 32);
  a3 += __shfl_xor(a3, 16); a3 += __shfl_xor(a3, 32);
  if (lane < 16) {
    float4 o;
    o.x = a0 * 0.25f + bb.x;
    o.y = a1 * 0.25f + bb.y;
    o.z = a2 * 0.25f + bb.z;
    o.w = a3 * 0.25f + bb.w;
    *(float4*)(out + (node << 6) + l4) = o;
  }
}

// ---------------- GATv2 layer 2: H=1, C=64; 4 edges/wave; f16 packed math ----------------
__global__ __launch_bounds__(TPB) void k_gat2(
    const unsigned short* __restrict__ xl, const unsigned short* __restrict__ xr,
    const int* __restrict__ rowoff, const int* __restrict__ deg,
    const int* __restrict__ csrc,
    const float* __restrict__ att, const float* __restrict__ bias,
    float* __restrict__ out, int N) {
  int node = (blockIdx.x * TPB + threadIdx.x) >> 6;
  int lane = threadIdx.x & 63;
  if (node >= N) return;
  int grp = lane >> 4, c4 = (lane & 15) * 4;
  float4 atv = *(const float4*)(att + c4);
  h2 at01, at23;
  at01.x = (_Float16)atv.x; at01.y = (_Float16)atv.y;
  at23.x = (_Float16)atv.z; at23.y = (_Float16)atv.w;
  float4 bb = *(const float4*)(bias + c4);
  uint2 rv = *(const uint2*)(xr + (node << 6) + c4);
  h2 xr01 = as_h2(rv.x), xr23 = as_h2(rv.y);
  const _Float16 c02 = (_Float16)0.2f;
  int beg = rowoff[node];
  int dg = deg[node];
  int endR = beg + dg;
  int quads = (dg + 3) >> 2;  // padded rows -> safe aligned reads
  float s = 0.f, a0 = 0.f, a1 = 0.f, a2 = 0.f, a3 = 0.f;
  for (int it = 0; it < quads; ++it) {
    int kk = beg + it * 4 + grp;
    int src = csrc[kk];                 // padding reads src=0 (valid row)
    bool ok = kk < endR;
    uint2 v = *(const uint2*)(xl + (src << 6) + c4);
    h2 x01 = as_h2(v.x), x23 = as_h2(v.y);
    h2 t01 = x01 + xr01, t23 = x23 + xr23;
    h2 l01 = __builtin_elementwise_max(t01, t01 * c02);
    h2 l23 = __builtin_elementwise_max(t23, t23 * c02);
    float p = __builtin_amdgcn_fdot2(l01, at01,
              __builtin_amdgcn_fdot2(l23, at23, 0.f, false), false);
    p = red16(p);
    float wv = ok ? __expf(p) : 0.f;
    s += wv;
    a0 += wv * (float)x01.x; a1 += wv * (float)x01.y;
    a2 += wv * (float)x23.x; a3 += wv * (float)x23.y;
  }
  // sum the 4 edge-groups
  s += __shfl_xor(s, 16); s += __shfl_xor(s, 32);
  a0 += __shfl_xor(a0, 16); a0 += __shfl_xor(a0, 32);
  a1 += __shfl_xor(a1, 16); a1 += __shfl_xor(a1, 32);
  a2 += __shfl_xor(a2, 16); a2 += __shfl_xor(a2, 32);
  a3 += __shfl_xor(a3, 16); a3 += __shfl_xor(a3, 32);
  if (lane < 16) {
    float inv = 1.f / (s + 1e-16f);
    float4 o;
    o.x = a0 * inv + bb.x;
    o.y = a1 * inv + bb.y;
    o.z = a2 * inv + bb.z;
    o.w = a3 * inv + bb.w;
    *(float4*)(out + (node << 6) + c4) = o;
  }
}

// ---------------- BatchNorm ----------------
__global__ void k_bnstat(const float* __restrict__ in, int N, float* __restrict__ part) {
  __shared__ float sm[TPB], sq[TPB];
  int col = threadIdx.x & 63;
  int rq = threadIdx.x >> 6;
  float s = 0.f, q = 0.f;
  for (int r = blockIdx.x * 4 + rq; r < N; r += gridDim.x * 4) {
    float v = in[(size_t)r * 64 + col];
    s += v; q += v * v;
  }
  sm[threadIdx.x] = s; sq[threadIdx.x] = q;
  __syncthreads();
  if (threadIdx.x < 64) {
    s = sm[threadIdx.x] + sm[threadIdx.x + 64] + sm[threadIdx.x + 128] + sm[threadIdx.x + 192];
    q = sq[threadIdx.x] + sq[threadIdx.x + 64] + sq[threadIdx.x + 128] + sq[threadIdx.x + 192];
    part[(size_t)blockIdx.x * 128 + threadIdx.x] = s;
    part[(size_t)blockIdx.x * 128 + 64 + threadIdx.x] = q;
  }
}

__global__ void k_bnfin(const float* __restrict__ part, int B, int N,
                        const float* __restrict__ g, const float* __restrict__ beta,
                        float* __restrict__ ab) {
  int c = threadIdx.x;  // 64 threads
  float s = 0.f, q = 0.f;
  for (int b = 0; b < B; ++b) {
    s += part[(size_t)b * 128 + c];
    q += part[(size_t)b * 128 + 64 + c];
  }
  float mean = s / (float)N;
  float var = q / (float)N - mean * mean;
  float a = g[c] * rsqrtf(var + 1e-5f);
  ab[c] = a;
  ab[64 + c] = beta[c] - mean * a;
}

// prep2: BN affine + relu + f16 (layer-2 GEMM input)
__global__ void k_prep2(const float* __restrict__ in, const float* __restrict__ ab,
                        unsigned short* __restrict__ o, int n4) {
  int i = blockIdx.x * blockDim.x + threadIdx.x;
  if (i >= n4) return;
  float4 v = *(const float4*)(in + (size_t)i * 4);
  int c0 = (i & 15) * 4;
  ushort4 u;
  u.x = f2h_bits(fmaxf(v.x * ab[c0 + 0] + ab[64 + c0 + 0], 0.f));
  u.y = f2h_bits(fmaxf(v.y * ab[c0 + 1] + ab[64 + c0 + 1], 0.f));
  u.z = f2h_bits(fmaxf(v.z * ab[c0 + 2] + ab[64 + c0 + 2], 0.f));
  u.w = f2h_bits(fmaxf(v.w * ab[c0 + 3] + ab[64 + c0 + 3], 0.f));
  *(ushort4*)(o + (size_t)i * 4) = u;
}

__global__ void k_bnapply(const float* __restrict__ in, const float* __restrict__ ab,
                          float* __restrict__ out, int total4) {
  int idx = blockIdx.x * blockDim.x + threadIdx.x;
  if (idx >= total4) return;
  float4 v = *(const float4*)(in + (size_t)idx * 4);
  int c0 = (idx & 15) * 4;
  v.x = fmaxf(v.x * ab[c0 + 0] + ab[64 + c0 + 0], 0.f);
  v.y = fmaxf(v.y * ab[c0 + 1] + ab[64 + c0 + 1], 0.f);
  v.z = fmaxf(v.z * ab[c0 + 2] + ab[64 + c0 + 2], 0.f);
  v.w = fmaxf(v.w * ab[c0 + 3] + ab[64 + c0 + 3], 0.f);
  *(float4*)(out + (size_t)idx * 4) = v;
}

extern "C" void kernel_launch(void* const* d_in, const int* in_sizes, int n_in,
                              void* d_out, int out_size, void* d_ws, size_t ws_size,
                              hipStream_t stream) {
  const float* x     = (const float*)d_in[0];
  const int*   ei    = (const int*)d_in[1];
  const float* Wl1   = (const float*)d_in[2];
  const float* bl1   = (const float*)d_in[3];
  const float* Wr1   = (const float*)d_in[4];
  const float* br1   = (const float*)d_in[5];
  const float* att1  = (const float*)d_in[6];
  const float* bias1 = (const float*)d_in[7];
  const float* g1    = (const float*)d_in[8];
  const float* be1   = (const float*)d_in[9];
  const float* Wl2   = (const float*)d_in[10];
  const float* bl2   = (const float*)d_in[11];
  const float* Wr2   = (const float*)d_in[12];
  const float* br2   = (const float*)d_in[13];
  const float* att2  = (const float*)d_in[14];
  const float* bias2 = (const float*)d_in[15];
  const float* g2    = (const float*)d_in[16];
  const float* be2   = (const float*)d_in[17];
  float* out = (float*)d_out;

  const int N  = in_sizes[0] / 128;   // 50000
  const int E  = in_sizes[1] / 2;     // 800000
  const int ET = E + N;
  const int ETP = ET + 4 * ((N + 255) & ~255);  // padded-CSR upper bound
  const int SB = (N + TPB - 1) / TPB; // 196 (<= TPB required)

  char* p = (char*)d_ws;
  auto take = [&](size_t b) { char* q = p; p += (b + 255) & ~(size_t)255; return q; };

  unsigned short* xl1 = (unsigned short*)take((size_t)N * 256 * 2);
  unsigned short* xr1 = (unsigned short*)take((size_t)N * 256 * 2);
  unsigned short* xl2 = (unsigned short*)take((size_t)N * 64 * 2);
  unsigned short* xr2 = (unsigned short*)take((size_t)N * 64 * 2);
  float* out1 = (float*)take((size_t)N * 64 * 4);
  unsigned short* xb = (unsigned short*)take((size_t)N * 128 * 2);  // reused as A2
  unsigned short* wt1l = (unsigned short*)take(256 * 128 * 2);
  unsigned short* wt1r = (unsigned short*)take(256 * 128 * 2);
  unsigned short* wt2l = (unsigned short*)take(64 * 64 * 2);
  unsigned short* wt2r = (unsigned short*)take(64 * 64 * 2);
  // deg and csrc adjacent -> one memset covers both
  int* deg    = (int*)take((size_t)N * 4);
  int* csrc   = (int*)take((size_t)ETP * 4 + 16);
  size_t zero_bytes = (char*)(csrc + ETP) + 16 - (char*)deg;
  int* rowoff = (int*)take((size_t)(N + 1) * 4);
  int* cursor = (int*)take((size_t)N * 4);
  int* bsum   = (int*)take((size_t)SB * 4);
  float* part = (float*)take((size_t)256 * 128 * 4);
  float* ab1  = (float*)take(128 * 4);
  float* ab2  = (float*)take(128 * 4);
  (void)ws_size; (void)n_in; (void)out_size;

  unsigned short* A2 = xb;  // layer-2 GEMM input aliases xb (dead after gemm1)

  int egrid = (ET + TPB - 1) / TPB;
  int nx4 = N * 32;                     // N*128/4
  int ptot = ET + nx4 + 73728;          // prep_all work items
  int ngrid = (N + 3) / 4;              // one node per wave, 4 waves/block
  int mtile = (N + 63) / 64;            // 782
  int total4 = N * 16;

  // CSR build (padded rows) + x/W f16 prep fused
  hipMemsetAsync(deg, 0, zero_bytes, stream);
  k_prep_all<<<(ptot + TPB - 1) / TPB, TPB, 0, stream>>>(
      ei, E, ET, deg, x, Wl1, Wr1, Wl2, Wr2, xb, wt1l, wt1r, wt2l, wt2r, nx4);
  k_scan1<<<SB, TPB, 0, stream>>>(deg, N, bsum);
  k_scan3<<<SB, TPB, 0, stream>>>(deg, bsum, SB, N, rowoff, cursor);
  k_fill<<<egrid, TPB, 0, stream>>>(ei, E, ET, cursor, csrc);

  // Layer 1
  k_gemm_mfma<<<dim3(mtile, 4), TPB, 3 * 64 * 128 * 2, stream>>>(
      xb, wt1l, bl1, wt1r, br1, xl1, xr1, N, 128, 256);
  k_gat1<<<ngrid, TPB, 0, stream>>>(xl1, xr1, rowoff, deg, csrc, att1, bias1, out1, N);
  k_bnstat<<<256, TPB, 0, stream>>>(out1, N, part);
  k_bnfin<<<1, 64, 0, stream>>>(part, 256, N, g1, be1, ab1);

  // Layer 2
  k_prep2<<<(total4 + TPB - 1) / TPB, TPB, 0, stream>>>(out1, ab1, A2, total4);
  k_gemm_mfma<<<dim3(mtile, 1), TPB, 3 * 64 * 64 * 2, stream>>>(
      A2, wt2l, bl2, wt2r, br2, xl2, xr2, N, 64, 64);
  k_gat2<<<ngrid, TPB, 0, stream>>>(xl2, xr2, rowoff, deg, csrc, att2, bias2, out, N);
  k_bnstat<<<256, TPB, 0, stream>>>(out, N, part);
  k_bnfin<<<1, 64, 0, stream>>>(part, 256, N, g2, be2, ab2);
  k_bnapply<<<(total4 + TPB - 1) / TPB, TPB, 0, stream>>>(out, ab2, out, total4);
}